// Round 4
// baseline (440.655 us; speedup 1.0000x reference)
//
#include <hip/hip_runtime.h>
#include <hip/hip_bf16.h>
#include <cstdint>
#include <cstddef>

// Problem constants
#define HW   512
#define HW2  1024
#define SZ   (512 * 512)
#define NPT  (34 * 34)   // 1156 warped 1024-res points per 16x16 output tile
#define K_PTS 5          // ceil(1156 / 256)
#define SRCW 36          // staged source window: 36x36
#define SRCP2 37         // padded row stride in float2 units
#define NSRC (SRCW * SRCW)
#define MARG 9           // window origin = tile_origin - MARG
#define TILW 35          // s_tile row stride: parity-split cols (0..16 even x, 17..33 odd x) + pad
#define NTIL (34 * TILW)

// jax.image.resize bilinear upsample 512->1024 taps for output index i (0..1023)
struct UpTap { int i0, i1; float w0, w1; };

__device__ __forceinline__ UpTap up_tap(int i) {
  UpTap t;
  int k = i >> 1;
  if ((i & 1) == 0) {
    t.i0 = k - 1; t.i1 = k; t.w0 = 0.25f; t.w1 = 0.75f;
    if (k == 0) { t.i0 = 0; t.w0 = 0.0f; t.w1 = 1.0f; }
  } else {
    t.i0 = k; t.i1 = k + 1; t.w0 = 0.75f; t.w1 = 0.25f;
    if (k == HW - 1) { t.i1 = HW - 1; t.w0 = 1.0f; t.w1 = 0.0f; }
  }
  return t;
}

__device__ __forceinline__ float up_at(const float* __restrict__ plane, int yi, int xi) {
  UpTap ty = up_tap(yi), tx = up_tap(xi);
  const float* r0 = plane + (size_t)ty.i0 * HW;
  const float* r1 = plane + (size_t)ty.i1 * HW;
  float v00 = r0[tx.i0], v01 = r0[tx.i1];
  float v10 = r1[tx.i0], v11 = r1[tx.i1];
  return ty.w0 * (tx.w0 * v00 + tx.w1 * v01) + ty.w1 * (tx.w0 * v10 + tx.w1 * v11);
}

// Separable decomposition of (warp-bilinear in 1024-space) o (2x upsample):
// a 3-tap stencil on the 512 grid.
__device__ __forceinline__ void axis_taps(float s, int& base, float& w0, float& w1, float& w2) {
  float f0 = floorf(s);
  int i0 = (int)f0;
  float fr = s - f0;
  int b = (i0 & 1) ? (i0 >> 1) : (i0 >> 1) - 1;
  b = b < 0 ? 0 : (b > (HW - 3) ? (HW - 3) : b);
  float w[3] = {0.0f, 0.0f, 0.0f};
  if ((unsigned)i0 < (unsigned)HW2) {
    UpTap t = up_tap(i0);
    w[t.i0 - b] += (1.0f - fr) * t.w0;
    w[t.i1 - b] += (1.0f - fr) * t.w1;
  }
  if ((unsigned)(i0 + 1) < (unsigned)HW2) {
    UpTap t = up_tap(i0 + 1);
    w[t.i0 - b] += fr * t.w0;
    w[t.i1 - b] += fr * t.w1;
  }
  base = b; w0 = w[0]; w1 = w[1]; w2 = w[2];
}

// Per-point separable 3x3 stencil. locoff >= 0: float2 index into staged window.
// locoff < 0: rare fallback, ~locoff = global by*HW+bx offset (displacement > ~8px).
struct PtTaps {
  int   locoff;
  float wy0, wy1, wy2, wx0, wx1, wx2;
};

__device__ __forceinline__ void compute_taps(const float* __restrict__ fx,
                                             const float* __restrict__ fy,
                                             int gx0, int gy0, int xo, int yo, int tid,
                                             PtTaps (&pt)[K_PTS]) {
  #pragma unroll
  for (int i = 0; i < K_PTS; ++i) {
    int p = tid + i * 256;
    pt[i].locoff = 0;
    pt[i].wy0 = pt[i].wy1 = pt[i].wy2 = 0.0f;
    pt[i].wx0 = pt[i].wx1 = pt[i].wx2 = 0.0f;
    if (p < NPT) {
      int ry = p / 34, rx = p % 34;
      int yy = gy0 + ry, xx = gx0 + rx;
      if ((unsigned)yy < (unsigned)HW2 && (unsigned)xx < (unsigned)HW2) {
        float sx = (float)xx + 2.0f * up_at(fx, yy, xx);
        float sy = (float)yy + 2.0f * up_at(fy, yy, xx);
        int bx, by;
        axis_taps(sx, bx, pt[i].wx0, pt[i].wx1, pt[i].wx2);
        axis_taps(sy, by, pt[i].wy0, pt[i].wy1, pt[i].wy2);
        int rx_ = bx - xo, ry_ = by - yo;
        if ((unsigned)rx_ <= (unsigned)(SRCW - 3) && (unsigned)ry_ <= (unsigned)(SRCW - 3))
          pt[i].locoff = ry_ * SRCP2 + rx_;         // float2 index, padded stride
        else
          pt[i].locoff = ~(by * HW + bx);           // fallback: global float offset
      }
    }
  }
}

// Stage a channel pair's 36x36 window into AoS float2 LDS (padded rows).
__device__ __forceinline__ void stage_pair(const float* __restrict__ p0,
                                           const float* __restrict__ p1,
                                           float2* __restrict__ s,
                                           int xo, int yo, int tid) {
  #pragma unroll
  for (int i = 0; i < 6; ++i) {                   // 6*256 = 1536 >= 1296
    int p = tid + i * 256;
    if (p < NSRC) {
      int r = p / SRCW, c = p % SRCW;
      int gy = yo + r; gy = gy < 0 ? 0 : (gy > HW - 1 ? HW - 1 : gy);
      int gx = xo + c; gx = gx < 0 ? 0 : (gx > HW - 1 ? HW - 1 : gx);
      size_t o = (size_t)gy * HW + gx;
      s[r * SRCP2 + c] = make_float2(p0[o], p1[o]);
    }
  }
}

__device__ __forceinline__ float eval3_global(const float* __restrict__ pl, int off, const PtTaps& t) {
  const float* p0 = pl + off;
  float r0 = t.wx0 * p0[0]        + t.wx1 * p0[1]          + t.wx2 * p0[2];
  float r1 = t.wx0 * p0[HW]       + t.wx1 * p0[HW + 1]     + t.wx2 * p0[HW + 2];
  float r2 = t.wx0 * p0[2 * HW]   + t.wx1 * p0[2 * HW + 1] + t.wx2 * p0[2 * HW + 2];
  return t.wy0 * r0 + t.wy1 * r1 + t.wy2 * r2;
}

// Evaluate all points from the AoS window into parity-split SoA tiles.
__device__ __forceinline__ void eval_round(const float2* __restrict__ s_src,
                                           float* __restrict__ t0,
                                           float* __restrict__ t1,
                                           const float* __restrict__ plane0,
                                           const float* __restrict__ plane1,
                                           const PtTaps (&pt)[K_PTS], int tid) {
  #pragma unroll
  for (int i = 0; i < K_PTS; ++i) {
    int p = tid + i * 256;
    if (p < NPT) {
      const PtTaps t = pt[i];
      float a0, a1;
      if (t.locoff >= 0) {
        const float2* s = s_src + t.locoff;
        float2 v00 = s[0],         v01 = s[1],             v02 = s[2];
        float2 v10 = s[SRCP2],     v11 = s[SRCP2 + 1],     v12 = s[SRCP2 + 2];
        float2 v20 = s[2 * SRCP2], v21 = s[2 * SRCP2 + 1], v22 = s[2 * SRCP2 + 2];
        float r00 = t.wx0 * v00.x + t.wx1 * v01.x + t.wx2 * v02.x;
        float r10 = t.wx0 * v10.x + t.wx1 * v11.x + t.wx2 * v12.x;
        float r20 = t.wx0 * v20.x + t.wx1 * v21.x + t.wx2 * v22.x;
        float r01 = t.wx0 * v00.y + t.wx1 * v01.y + t.wx2 * v02.y;
        float r11 = t.wx0 * v10.y + t.wx1 * v11.y + t.wx2 * v12.y;
        float r21 = t.wx0 * v20.y + t.wx1 * v21.y + t.wx2 * v22.y;
        a0 = t.wy0 * r00 + t.wy1 * r10 + t.wy2 * r20;
        a1 = t.wy0 * r01 + t.wy1 * r11 + t.wy2 * r21;
      } else {                                     // ~never taken (|disp| > ~8px)
        int off = ~t.locoff;
        a0 = eval3_global(plane0, off, t);
        a1 = eval3_global(plane1, off, t);
      }
      // parity-split store: col (rx>>1) for even x, 17+(rx>>1) for odd x
      int ry = p / 34, rx = p - ry * 34;
      int ti = ry * TILW + (rx >> 1) + ((rx & 1) ? 17 : 0);
      t0[ti] = a0;
      t1[ti] = a1;
    }
  }
}

// -------------------- K1/K4: res_warp_img(tgt, res_field, rollback=1) --------------------
// AoS float2 s_src (round-1 proven); parity-split SoA s_tile (phase-3 4-way -> 2-way);
// XCD-chunked block swizzle; K1 additionally folds the src-channel passthrough copy.
// NOTE: no min-waves launch bound — (256,8) forced VGPR<=64 and spilled pt[] (round 2).
__global__ void __launch_bounds__(256)
warp_img_kernel(const float* __restrict__ x,    // [B,32,512,512]
                const float* __restrict__ res,  // [B,2,512,512]
                float* __restrict__ out,        // [B,32,512,512]
                int docopy)
{
  __shared__ float2 s_src[36 * SRCP2];  // 10656 B
  __shared__ float  s_tile0[NTIL];      //  4760 B each -> 20176 B total
  __shared__ float  s_tile1[NTIL];

  // XCD-chunked swizzle: 2048 blocks, 8 XCDs, 256 per chunk (bijective).
  const int lin = blockIdx.x;
  const int t = (lin & 7) * 256 + (lin >> 3);
  const int b = t >> 10;
  const int by = (t >> 5) & 31, bx = t & 31;
  const int tx0 = bx * 16, ty0 = by * 16;
  const int gx0 = tx0 * 2 - 1, gy0 = ty0 * 2 - 1;
  const int xo = tx0 - MARG, yo = ty0 - MARG;
  const int tid = threadIdx.x;

  const float* resx = res + (size_t)b * 2 * SZ;
  const float* resy = resx + SZ;
  const float* tgt  = x + ((size_t)b * 32 + 16) * SZ;

  // Issue staging loads for round 0 first so they fly under tap computation.
  stage_pair(tgt, tgt + SZ, s_src, xo, yo, tid);

  PtTaps pt[K_PTS];
  compute_taps(resx, resy, gx0, gy0, xo, yo, tid, pt);

  const int ly = tid >> 4, lx = tid & 15;
  const int oy = ty0 + ly, ox = tx0 + lx;
  const float RW[4] = {0.25f, 0.75f, 0.75f, 0.25f};
  float wy[4], wx[4];
  float sumy = 0.f, sumx = 0.f;
  #pragma unroll
  for (int d = 0; d < 4; ++d) {
    int g = 2 * oy - 1 + d;
    wy[d] = ((unsigned)g < (unsigned)HW2) ? RW[d] : 0.0f; sumy += wy[d];
    g = 2 * ox - 1 + d;
    wx[d] = ((unsigned)g < (unsigned)HW2) ? RW[d] : 0.0f; sumx += wx[d];
  }
  const float inv = 1.0f / (sumy * sumx);
  const size_t pixoff = (size_t)oy * HW + ox;

  __syncthreads();                                 // s_src round 0 ready

  for (int c = 0; c < 16; c += 2) {
    const float* plane0 = tgt + (size_t)c * SZ;
    eval_round(s_src, s_tile0, s_tile1, plane0, plane0 + SZ, pt, tid);
    __syncthreads();                               // s_tile ready; s_src free

    if (c < 14)                                    // overlap next staging with phase 3
      stage_pair(plane0 + 2 * SZ, plane0 + 3 * SZ, s_src, xo, yo, tid);

    // folded K0: passthrough copy of src channels c, c+1 (K1 only)
    float cp0 = 0.f, cp1 = 0.f;
    if (docopy) {
      const float* sp = x + ((size_t)b * 32 + c) * SZ + pixoff;
      cp0 = sp[0];
      cp1 = sp[SZ];
    }

    float acc0 = 0.0f, acc1 = 0.0f;
    #pragma unroll
    for (int dy = 0; dy < 4; ++dy) {
      const int rbase = (2 * ly + dy) * TILW;
      // dx=0 -> even col lx; dx=1 -> odd col 17+lx; dx=2 -> even lx+1; dx=3 -> odd 18+lx
      float a0 = s_tile0[rbase + lx],     b0 = s_tile0[rbase + 17 + lx];
      float c0 = s_tile0[rbase + lx + 1], d0 = s_tile0[rbase + 18 + lx];
      float a1 = s_tile1[rbase + lx],     b1 = s_tile1[rbase + 17 + lx];
      float c1 = s_tile1[rbase + lx + 1], d1 = s_tile1[rbase + 18 + lx];
      float r0 = wx[0] * a0 + wx[1] * b0 + wx[2] * c0 + wx[3] * d0;
      float r1 = wx[0] * a1 + wx[1] * b1 + wx[2] * c1 + wx[3] * d1;
      acc0 += wy[dy] * r0;
      acc1 += wy[dy] * r1;
    }
    size_t o = ((size_t)b * 32 + 16 + c) * SZ + pixoff;
    out[o] = acc0 * inv;
    out[o + SZ] = acc1 * inv;
    if (docopy) {
      size_t oc = ((size_t)b * 32 + c) * SZ + pixoff;
      out[oc] = cp0;
      out[oc + SZ] = cp1;
    }
    __syncthreads();                               // s_src(next) ready; s_tile free
  }
}

// -------------------- K2: 3x3 conv over 50-ch bundle -> 2-ch adj --------------------
// LDS-staged halo (zero-filled), double-buffered with register round-trip (T14 split).
#define CHN 18                     // halo width (16 + 2)
#define CHE (CHN * CHN)            // 324 elements

__global__ void __launch_bounds__(256)
conv_kernel(const float* __restrict__ x,
            const float* __restrict__ warped,  // = out, ch 16..31
            const float* __restrict__ res,
            const float* __restrict__ Wc,      // [2,50,3,3]
            const float* __restrict__ bc,      // [2]
            float* __restrict__ adj)           // [B,2,512,512]
{
  __shared__ float sw[900];
  __shared__ float sh[2][CHE];

  const int tid = threadIdx.x;
  for (int i = tid; i < 900; i += 256) sw[i] = Wc[i];

  const int b = blockIdx.z;
  const int tx0 = blockIdx.x * 16, ty0 = blockIdx.y * 16;
  const int ty = tid >> 4, tx = tid & 15;

  float acc0 = bc[0];
  float acc1 = bc[1];

  const float* px = x + (size_t)b * 32 * SZ;
  const float* pw = warped + ((size_t)b * 32 + 16) * SZ;
  const float* pr = res + (size_t)b * 2 * SZ;

  #define PLANE(ic) ((ic) < 32 ? px + (size_t)(ic) * SZ \
                   : (ic) < 48 ? pw + (size_t)((ic) - 32) * SZ \
                   : pr + (size_t)((ic) - 48) * SZ)

  float rb0, rb1;
  {  // stage plane 0
    const float* pl = PLANE(0);
    rb0 = 0.f; rb1 = 0.f;
    int p = tid;
    { int ry = p / CHN, rx = p % CHN;
      int gy = ty0 - 1 + ry, gx = tx0 - 1 + rx;
      if ((unsigned)gy < (unsigned)HW && (unsigned)gx < (unsigned)HW) rb0 = pl[(size_t)gy * HW + gx]; }
    p = tid + 256;
    if (p < CHE) {
      int ry = p / CHN, rx = p % CHN;
      int gy = ty0 - 1 + ry, gx = tx0 - 1 + rx;
      if ((unsigned)gy < (unsigned)HW && (unsigned)gx < (unsigned)HW) rb1 = pl[(size_t)gy * HW + gx];
    }
    sh[0][tid] = rb0;
    if (tid + 256 < CHE) sh[0][tid + 256] = rb1;
  }

  for (int ic = 0; ic < 50; ++ic) {
    __syncthreads();                      // sh[ic&1] ready (and prev writes drained)
    if (ic < 49) {                        // issue next plane's loads before compute
      const float* pl = PLANE(ic + 1);
      rb0 = 0.f; rb1 = 0.f;
      int p = tid;
      { int ry = p / CHN, rx = p % CHN;
        int gy = ty0 - 1 + ry, gx = tx0 - 1 + rx;
        if ((unsigned)gy < (unsigned)HW && (unsigned)gx < (unsigned)HW) rb0 = pl[(size_t)gy * HW + gx]; }
      p = tid + 256;
      if (p < CHE) {
        int ry = p / CHN, rx = p % CHN;
        int gy = ty0 - 1 + ry, gx = tx0 - 1 + rx;
        if ((unsigned)gy < (unsigned)HW && (unsigned)gx < (unsigned)HW) rb1 = pl[(size_t)gy * HW + gx];
      }
    }

    const float* hp = sh[ic & 1];
    const float* w0 = &sw[ic * 9];
    const float* w1 = &sw[450 + ic * 9];
    #pragma unroll
    for (int ky = 0; ky < 3; ++ky) {
      #pragma unroll
      for (int kx = 0; kx < 3; ++kx) {
        float v = hp[(ty + ky) * CHN + tx + kx];
        acc0 += v * w0[ky * 3 + kx];
        acc1 += v * w1[ky * 3 + kx];
      }
    }

    if (ic < 49) {                        // write-late into the other buffer
      float* sd = sh[(ic + 1) & 1];
      sd[tid] = rb0;
      if (tid + 256 < CHE) sd[tid + 256] = rb1;
    }
  }
  #undef PLANE

  const int oy = ty0 + ty, ox = tx0 + tx;
  adj[((size_t)b * 2 + 0) * SZ + (size_t)oy * HW + ox] = acc0;
  adj[((size_t)b * 2 + 1) * SZ + (size_t)oy * HW + ox] = acc1;
}

// -------------------- K3: new_res = adj + downsample(warp(up(res), 2*up(adj))) --------------------
__global__ void __launch_bounds__(256)
new_res_kernel(const float* __restrict__ res,  // [B,2,512,512]
               const float* __restrict__ adj,  // [B,2,512,512]
               float* __restrict__ nres)       // [B,2,512,512]
{
  __shared__ float2 s_src[36 * SRCP2];
  __shared__ float  s_tile0[NTIL];
  __shared__ float  s_tile1[NTIL];

  const int lin = blockIdx.x;
  const int t = (lin & 7) * 256 + (lin >> 3);
  const int b = t >> 10;
  const int by = (t >> 5) & 31, bx = t & 31;
  const int tx0 = bx * 16, ty0 = by * 16;
  const int gx0 = tx0 * 2 - 1, gy0 = ty0 * 2 - 1;
  const int xo = tx0 - MARG, yo = ty0 - MARG;
  const int tid = threadIdx.x;

  const float* adjx = adj + (size_t)b * 2 * SZ;
  const float* adjy = adjx + SZ;
  const float* res0 = res + (size_t)b * 2 * SZ;
  const float* res1 = res0 + SZ;

  stage_pair(res0, res1, s_src, xo, yo, tid);

  PtTaps pt[K_PTS];
  compute_taps(adjx, adjy, gx0, gy0, xo, yo, tid, pt);

  const int ly = tid >> 4, lx = tid & 15;
  const int oy = ty0 + ly, ox = tx0 + lx;
  const float RW[4] = {0.25f, 0.75f, 0.75f, 0.25f};
  float wy[4], wx[4];
  float sumy = 0.f, sumx = 0.f;
  #pragma unroll
  for (int d = 0; d < 4; ++d) {
    int g = 2 * oy - 1 + d;
    wy[d] = ((unsigned)g < (unsigned)HW2) ? RW[d] : 0.0f; sumy += wy[d];
    g = 2 * ox - 1 + d;
    wx[d] = ((unsigned)g < (unsigned)HW2) ? RW[d] : 0.0f; sumx += wx[d];
  }
  const float inv = 1.0f / (sumy * sumx);

  __syncthreads();
  eval_round(s_src, s_tile0, s_tile1, res0, res1, pt, tid);
  __syncthreads();

  float acc0 = 0.0f, acc1 = 0.0f;
  #pragma unroll
  for (int dy = 0; dy < 4; ++dy) {
    const int rbase = (2 * ly + dy) * TILW;
    float a0 = s_tile0[rbase + lx],     b0 = s_tile0[rbase + 17 + lx];
    float c0 = s_tile0[rbase + lx + 1], d0 = s_tile0[rbase + 18 + lx];
    float a1 = s_tile1[rbase + lx],     b1 = s_tile1[rbase + 17 + lx];
    float c1 = s_tile1[rbase + lx + 1], d1 = s_tile1[rbase + 18 + lx];
    float r0 = wx[0] * a0 + wx[1] * b0 + wx[2] * c0 + wx[3] * d0;
    float r1 = wx[0] * a1 + wx[1] * b1 + wx[2] * c1 + wx[3] * d1;
    acc0 += wy[dy] * r0;
    acc1 += wy[dy] * r1;
  }
  size_t o = ((size_t)b * 2) * SZ + (size_t)oy * HW + ox;
  nres[o]      = acc0 * inv + adjx[(size_t)oy * HW + ox];
  nres[o + SZ] = acc1 * inv + adjy[(size_t)oy * HW + ox];
}

extern "C" void kernel_launch(void* const* d_in, const int* in_sizes, int n_in,
                              void* d_out, int out_size, void* d_ws, size_t ws_size,
                              hipStream_t stream) {
  const float* x   = (const float*)d_in[0];  // [2,32,512,512] f32
  const float* res = (const float*)d_in[1];  // [2,2,512,512]  f32
  const float* Wc  = (const float*)d_in[2];  // [2,50,3,3]     f32
  const float* bc  = (const float*)d_in[3];  // [2]            f32
  float* out = (float*)d_out;                // [2,32,512,512] f32

  float* adj  = (float*)d_ws;                // [2,2,512,512]
  float* nres = adj + (size_t)2 * 2 * SZ;    // [2,2,512,512]

  // K1: warped_tgt -> out ch 16..31, plus folded src passthrough (ch 0..15)
  warp_img_kernel<<<dim3(2048), dim3(256), 0, stream>>>(x, res, out, 1);

  // K2: conv3x3 over [x(0..31) | out(16..31) | res] -> adj
  conv_kernel<<<dim3(32, 32, 2), dim3(256), 0, stream>>>(x, out, res, Wc, bc, adj);

  // K3: new_res
  new_res_kernel<<<dim3(2048), dim3(256), 0, stream>>>(res, adj, nres);

  // K4: hindsight warp -> out channels 16..31 (overwrites staging)
  warp_img_kernel<<<dim3(2048), dim3(256), 0, stream>>>(x, nres, out, 0);
}

// Round 5
// 377.421 us; speedup vs baseline: 1.1675x; 1.1675x over previous
//
#include <hip/hip_runtime.h>
#include <hip/hip_bf16.h>
#include <cstdint>
#include <cstddef>

// Problem constants
#define HW   512
#define HW2  1024
#define SZ   (512 * 512)
#define NPT  (34 * 34)   // 1156 warped 1024-res points per 16x16 output tile
#define K_PTS 5          // ceil(1156 / 256)
#define SRCW 36          // staged source window: 36x36
#define NSRC (SRCW * SRCW)   // 1296
#define MARG 9           // window origin = tile_origin - MARG

// jax.image.resize bilinear upsample 512->1024 taps for output index i (0..1023)
struct UpTap { int i0, i1; float w0, w1; };

__device__ __forceinline__ UpTap up_tap(int i) {
  UpTap t;
  int k = i >> 1;
  if ((i & 1) == 0) {
    t.i0 = k - 1; t.i1 = k; t.w0 = 0.25f; t.w1 = 0.75f;
    if (k == 0) { t.i0 = 0; t.w0 = 0.0f; t.w1 = 1.0f; }
  } else {
    t.i0 = k; t.i1 = k + 1; t.w0 = 0.75f; t.w1 = 0.25f;
    if (k == HW - 1) { t.i1 = HW - 1; t.w0 = 1.0f; t.w1 = 0.0f; }
  }
  return t;
}

__device__ __forceinline__ float up_at(const float* __restrict__ plane, int yi, int xi) {
  UpTap ty = up_tap(yi), tx = up_tap(xi);
  const float* r0 = plane + (size_t)ty.i0 * HW;
  const float* r1 = plane + (size_t)ty.i1 * HW;
  float v00 = r0[tx.i0], v01 = r0[tx.i1];
  float v10 = r1[tx.i0], v11 = r1[tx.i1];
  return ty.w0 * (tx.w0 * v00 + tx.w1 * v01) + ty.w1 * (tx.w0 * v10 + tx.w1 * v11);
}

// Separable decomposition of (warp-bilinear in 1024-space) o (2x upsample):
// a 3-tap stencil on the 512 grid. Base clamped to [0,509]; out-of-range
// corners get weight 0 (zero padding, mask pre-clamp).
__device__ __forceinline__ void axis_taps(float s, int& base, float& w0, float& w1, float& w2) {
  float f0 = floorf(s);
  int i0 = (int)f0;
  float fr = s - f0;
  int b = (i0 & 1) ? (i0 >> 1) : (i0 >> 1) - 1;
  b = b < 0 ? 0 : (b > (HW - 3) ? (HW - 3) : b);
  float w[3] = {0.0f, 0.0f, 0.0f};
  if ((unsigned)i0 < (unsigned)HW2) {
    UpTap t = up_tap(i0);
    w[t.i0 - b] += (1.0f - fr) * t.w0;
    w[t.i1 - b] += (1.0f - fr) * t.w1;
  }
  if ((unsigned)(i0 + 1) < (unsigned)HW2) {
    UpTap t = up_tap(i0 + 1);
    w[t.i0 - b] += fr * t.w0;
    w[t.i1 - b] += fr * t.w1;
  }
  base = b; w0 = w[0]; w1 = w[1]; w2 = w[2];
}

// Per-point separable 3x3 stencil. locoff >= 0: index into staged 36x36 LDS window.
// locoff < 0: rare fallback, ~locoff = global by*HW+bx offset (displacement > ~8px).
struct PtTaps {
  int   locoff;
  float wy0, wy1, wy2, wx0, wx1, wx2;
};

__device__ __forceinline__ void compute_taps(const float* __restrict__ fx,
                                             const float* __restrict__ fy,
                                             int gx0, int gy0, int xo, int yo, int tid,
                                             PtTaps (&pt)[K_PTS]) {
  #pragma unroll
  for (int i = 0; i < K_PTS; ++i) {
    int p = tid + i * 256;
    pt[i].locoff = 0;
    pt[i].wy0 = pt[i].wy1 = pt[i].wy2 = 0.0f;
    pt[i].wx0 = pt[i].wx1 = pt[i].wx2 = 0.0f;
    if (p < NPT) {
      int ry = p / 34, rx = p % 34;
      int yy = gy0 + ry, xx = gx0 + rx;
      if ((unsigned)yy < (unsigned)HW2 && (unsigned)xx < (unsigned)HW2) {
        float sx = (float)xx + 2.0f * up_at(fx, yy, xx);
        float sy = (float)yy + 2.0f * up_at(fy, yy, xx);
        int bx, by;
        axis_taps(sx, bx, pt[i].wx0, pt[i].wx1, pt[i].wx2);
        axis_taps(sy, by, pt[i].wy0, pt[i].wy1, pt[i].wy2);
        int rx_ = bx - xo, ry_ = by - yo;
        if ((unsigned)rx_ <= (unsigned)(SRCW - 3) && (unsigned)ry_ <= (unsigned)(SRCW - 3))
          pt[i].locoff = ry_ * SRCW + rx_;          // in staged window
        else
          pt[i].locoff = ~(by * HW + bx);           // fallback: global offset
      }
    }
  }
}

// Stage a channel pair's 36x36 source window into LDS (float2 interleaved).
__device__ __forceinline__ void stage_pair(const float* __restrict__ p0,
                                           const float* __restrict__ p1,
                                           float2* __restrict__ s_src,
                                           int xo, int yo, int tid) {
  #pragma unroll
  for (int i = 0; i < 6; ++i) {                   // 6*256 = 1536 >= 1296
    int p = tid + i * 256;
    if (p < NSRC) {
      int r = p / SRCW, c = p % SRCW;
      int gy = yo + r; gy = gy < 0 ? 0 : (gy > HW - 1 ? HW - 1 : gy);
      int gx = xo + c; gx = gx < 0 ? 0 : (gx > HW - 1 ? HW - 1 : gx);
      size_t o = (size_t)gy * HW + gx;
      s_src[p] = make_float2(p0[o], p1[o]);
    }
  }
}

__device__ __forceinline__ float eval3_global(const float* __restrict__ pl, int off, const PtTaps& t) {
  const float* p0 = pl + off;
  float r0 = t.wx0 * p0[0]        + t.wx1 * p0[1]          + t.wx2 * p0[2];
  float r1 = t.wx0 * p0[HW]       + t.wx1 * p0[HW + 1]     + t.wx2 * p0[HW + 2];
  float r2 = t.wx0 * p0[2 * HW]   + t.wx1 * p0[2 * HW + 1] + t.wx2 * p0[2 * HW + 2];
  return t.wy0 * r0 + t.wy1 * r1 + t.wy2 * r2;
}

// Evaluate all points of a channel pair from the staged LDS window into s_tile.
__device__ __forceinline__ void eval_round(const float2* __restrict__ s_src,
                                           float2* __restrict__ s_tile,
                                           const float* __restrict__ plane0,
                                           const float* __restrict__ plane1,
                                           const PtTaps (&pt)[K_PTS], int tid) {
  #pragma unroll
  for (int i = 0; i < K_PTS; ++i) {
    int p = tid + i * 256;
    if (p < NPT) {
      const PtTaps t = pt[i];
      float a0, a1;
      if (t.locoff >= 0) {
        const float2* s = s_src + t.locoff;
        float2 v00 = s[0],        v01 = s[1],            v02 = s[2];
        float2 v10 = s[SRCW],     v11 = s[SRCW + 1],     v12 = s[SRCW + 2];
        float2 v20 = s[2 * SRCW], v21 = s[2 * SRCW + 1], v22 = s[2 * SRCW + 2];
        float r00 = t.wx0 * v00.x + t.wx1 * v01.x + t.wx2 * v02.x;
        float r10 = t.wx0 * v10.x + t.wx1 * v11.x + t.wx2 * v12.x;
        float r20 = t.wx0 * v20.x + t.wx1 * v21.x + t.wx2 * v22.x;
        float r01 = t.wx0 * v00.y + t.wx1 * v01.y + t.wx2 * v02.y;
        float r11 = t.wx0 * v10.y + t.wx1 * v11.y + t.wx2 * v12.y;
        float r21 = t.wx0 * v20.y + t.wx1 * v21.y + t.wx2 * v22.y;
        a0 = t.wy0 * r00 + t.wy1 * r10 + t.wy2 * r20;
        a1 = t.wy0 * r01 + t.wy1 * r11 + t.wy2 * r21;
      } else {                                     // ~never taken (|disp| > ~8px)
        int off = ~t.locoff;
        a0 = eval3_global(plane0, off, t);
        a1 = eval3_global(plane1, off, t);
      }
      s_tile[p] = make_float2(a0, a1);
    }
  }
}

// -------------------- K1/K4: res_warp_img(tgt, res_field, rollback=1) --------------------
// VERBATIM round-1 structure: AoS float2, unpadded, no swizzle, no fold.
// This compiled to VGPR=64 (the occupancy cliff: >64 halves waves/EU, m69) -> 113 us.
__global__ void warp_img_kernel(const float* __restrict__ x,    // [B,32,512,512]
                                const float* __restrict__ res,  // [B,2,512,512]
                                float* __restrict__ out)        // [B,32,512,512]
{
  __shared__ float2 s_src[NSRC];   // 10368 B
  __shared__ float2 s_tile[NPT];   //  9248 B

  const int b = blockIdx.z;
  const int tx0 = blockIdx.x * 16, ty0 = blockIdx.y * 16;
  const int gx0 = tx0 * 2 - 1, gy0 = ty0 * 2 - 1;
  const int xo = tx0 - MARG, yo = ty0 - MARG;
  const int tid = threadIdx.x;

  const float* resx = res + (size_t)b * 2 * SZ;
  const float* resy = resx + SZ;
  const float* tgt  = x + ((size_t)b * 32 + 16) * SZ;

  // Issue staging loads for round 0 first so they fly under tap computation.
  stage_pair(tgt, tgt + SZ, s_src, xo, yo, tid);

  PtTaps pt[K_PTS];
  compute_taps(resx, resy, gx0, gy0, xo, yo, tid, pt);

  // Downsample stencil weights for this thread's output pixel
  const int ly = tid >> 4, lx = tid & 15;
  const int oy = ty0 + ly, ox = tx0 + lx;
  const float RW[4] = {0.25f, 0.75f, 0.75f, 0.25f};
  float wy[4], wx[4];
  float sumy = 0.f, sumx = 0.f;
  #pragma unroll
  for (int d = 0; d < 4; ++d) {
    int g = 2 * oy - 1 + d;
    wy[d] = ((unsigned)g < (unsigned)HW2) ? RW[d] : 0.0f; sumy += wy[d];
    g = 2 * ox - 1 + d;
    wx[d] = ((unsigned)g < (unsigned)HW2) ? RW[d] : 0.0f; sumx += wx[d];
  }
  const float inv = 1.0f / (sumy * sumx);

  __syncthreads();                                 // s_src round 0 ready

  for (int c = 0; c < 16; c += 2) {
    const float* plane0 = tgt + (size_t)c * SZ;
    eval_round(s_src, s_tile, plane0, plane0 + SZ, pt, tid);
    __syncthreads();                               // s_tile ready; s_src free

    if (c < 14)                                    // overlap next staging with phase 3
      stage_pair(plane0 + 2 * SZ, plane0 + 3 * SZ, s_src, xo, yo, tid);

    float acc0 = 0.0f, acc1 = 0.0f;
    #pragma unroll
    for (int dy = 0; dy < 4; ++dy) {
      float r0 = 0.0f, r1 = 0.0f;
      const int base = (2 * ly + dy) * 34 + 2 * lx;
      #pragma unroll
      for (int dx = 0; dx < 4; ++dx) {
        float2 v = s_tile[base + dx];
        r0 += wx[dx] * v.x;
        r1 += wx[dx] * v.y;
      }
      acc0 += wy[dy] * r0;
      acc1 += wy[dy] * r1;
    }
    size_t o = (((size_t)b * 32 + 16 + c) * HW + oy) * HW + ox;
    out[o] = acc0 * inv;
    out[o + SZ] = acc1 * inv;
    __syncthreads();                               // s_src(next) ready; s_tile free
  }
}

// -------------------- K2: 3x3 conv over 50-ch bundle -> 2-ch adj --------------------
// Pair-processed (25 iters x 2 planes prefetched; halves barrier/latency serialization)
// + fused src passthrough: out ch 0..15 = x ch 0..15, written from the already-loaded
// center tap (ky=1,kx=1) of the staged halo -- replaces the separate copy_src kernel.
#define CHN 18                     // halo width (16 + 2)
#define CHE (CHN * CHN)            // 324 elements

__global__ void __launch_bounds__(256)
conv_kernel(const float* __restrict__ x,
            const float* __restrict__ res,
            const float* __restrict__ Wc,      // [2,50,3,3]
            const float* __restrict__ bc,      // [2]
            float* __restrict__ out,           // [B,32,512,512]: reads ch16..31 (warped), writes ch0..15
            float* __restrict__ adj)           // [B,2,512,512]
{
  __shared__ float sw[900];
  __shared__ float sh[4][CHE];     // two pair-buffers

  const int tid = threadIdx.x;
  for (int i = tid; i < 900; i += 256) sw[i] = Wc[i];

  const int b = blockIdx.z;
  const int tx0 = blockIdx.x * 16, ty0 = blockIdx.y * 16;
  const int ty = tid >> 4, tx = tid & 15;

  const float* px = x + (size_t)b * 32 * SZ;
  const float* pw = out + ((size_t)b * 32 + 16) * SZ;
  const float* pr = res + (size_t)b * 2 * SZ;

  // Halo-slot addressing (identical for every plane; computed once)
  const int ry0 = tid / CHN, rx0 = tid - ry0 * CHN;
  const int hy0 = ty0 - 1 + ry0, hx0 = tx0 - 1 + rx0;
  const bool ok0 = (unsigned)hy0 < (unsigned)HW && (unsigned)hx0 < (unsigned)HW;
  const int off0 = hy0 * HW + hx0;               // only deref'd under ok0
  const int p1 = tid + 256;
  const bool sl1 = p1 < CHE;                     // tid < 68
  const int ry1 = p1 / CHN, rx1 = p1 - ry1 * CHN;
  const int hy1 = ty0 - 1 + ry1, hx1 = tx0 - 1 + rx1;
  const bool ok1 = sl1 && (unsigned)hy1 < (unsigned)HW && (unsigned)hx1 < (unsigned)HW;
  const int off1 = hy1 * HW + hx1;

  #define PLANE(ic) ((ic) < 32 ? px + (size_t)(ic) * SZ \
                   : (ic) < 48 ? pw + (size_t)((ic) - 32) * SZ \
                   : pr + (size_t)((ic) - 48) * SZ)

  float acc0 = bc[0];
  float acc1 = bc[1];

  {  // prologue: stage pair 0 (planes 0,1) into sh[0], sh[1]
    const float* plE = PLANE(0);
    const float* plO = PLANE(1);
    float e0 = ok0 ? plE[off0] : 0.f;
    float e1 = ok1 ? plE[off1] : 0.f;
    float o0 = ok0 ? plO[off0] : 0.f;
    float o1 = ok1 ? plO[off1] : 0.f;
    sh[0][tid] = e0; if (sl1) sh[0][p1] = e1;
    sh[1][tid] = o0; if (sl1) sh[1][p1] = o1;
  }

  const size_t pix = (size_t)(ty0 + ty) * HW + (tx0 + tx);

  for (int kk = 0; kk < 25; ++kk) {
    __syncthreads();                      // current pair ready; other pair free
    float e0 = 0.f, e1 = 0.f, o0 = 0.f, o1 = 0.f;
    if (kk < 24) {                        // issue next pair's loads before compute (T14)
      const float* plE = PLANE(2 * kk + 2);
      const float* plO = PLANE(2 * kk + 3);
      e0 = ok0 ? plE[off0] : 0.f;
      e1 = ok1 ? plE[off1] : 0.f;
      o0 = ok0 ? plO[off0] : 0.f;
      o1 = ok1 ? plO[off1] : 0.f;
    }

    const int cur = (kk & 1) * 2;
    const float* hpE = sh[cur];
    const float* hpO = sh[cur + 1];
    const float* wE0 = &sw[(2 * kk) * 9];
    const float* wO0 = wE0 + 9;
    const float* wE1 = &sw[450 + (2 * kk) * 9];
    const float* wO1 = wE1 + 9;
    float cE = 0.f, cO = 0.f;
    #pragma unroll
    for (int ky = 0; ky < 3; ++ky) {
      #pragma unroll
      for (int kx = 0; kx < 3; ++kx) {
        float vE = hpE[(ty + ky) * CHN + tx + kx];
        float vO = hpO[(ty + ky) * CHN + tx + kx];
        if (ky == 1 && kx == 1) { cE = vE; cO = vO; }
        acc0 += vE * wE0[ky * 3 + kx];
        acc0 += vO * wO0[ky * 3 + kx];
        acc1 += vE * wE1[ky * 3 + kx];
        acc1 += vO * wO1[ky * 3 + kx];
      }
    }

    if (kk < 8) {                         // fused K0: out ch 2kk, 2kk+1 = x ch 2kk, 2kk+1
      size_t oc = ((size_t)b * 32 + 2 * kk) * SZ + pix;
      out[oc] = cE;
      out[oc + SZ] = cO;
    }

    if (kk < 24) {                        // write-late into the other pair-buffer
      float* sE = sh[cur ^ 2];
      float* sO = sh[(cur ^ 2) + 1];
      sE[tid] = e0; if (sl1) sE[p1] = e1;
      sO[tid] = o0; if (sl1) sO[p1] = o1;
    }
  }
  #undef PLANE

  adj[((size_t)b * 2 + 0) * SZ + pix] = acc0;
  adj[((size_t)b * 2 + 1) * SZ + pix] = acc1;
}

// -------------------- K3: new_res = adj + downsample(warp(up(res), 2*up(adj))) --------------------
// (the reference's *2 on the warped field values and the *0.5 after downsample cancel exactly)
__global__ void new_res_kernel(const float* __restrict__ res,  // [B,2,512,512]
                               const float* __restrict__ adj,  // [B,2,512,512]
                               float* __restrict__ nres)       // [B,2,512,512]
{
  __shared__ float2 s_src[NSRC];
  __shared__ float2 s_tile[NPT];

  const int b = blockIdx.z;
  const int tx0 = blockIdx.x * 16, ty0 = blockIdx.y * 16;
  const int gx0 = tx0 * 2 - 1, gy0 = ty0 * 2 - 1;
  const int xo = tx0 - MARG, yo = ty0 - MARG;
  const int tid = threadIdx.x;

  const float* adjx = adj + (size_t)b * 2 * SZ;
  const float* adjy = adjx + SZ;
  const float* res0 = res + (size_t)b * 2 * SZ;
  const float* res1 = res0 + SZ;

  stage_pair(res0, res1, s_src, xo, yo, tid);

  PtTaps pt[K_PTS];
  compute_taps(adjx, adjy, gx0, gy0, xo, yo, tid, pt);

  const int ly = tid >> 4, lx = tid & 15;
  const int oy = ty0 + ly, ox = tx0 + lx;
  const float RW[4] = {0.25f, 0.75f, 0.75f, 0.25f};
  float wy[4], wx[4];
  float sumy = 0.f, sumx = 0.f;
  #pragma unroll
  for (int d = 0; d < 4; ++d) {
    int g = 2 * oy - 1 + d;
    wy[d] = ((unsigned)g < (unsigned)HW2) ? RW[d] : 0.0f; sumy += wy[d];
    g = 2 * ox - 1 + d;
    wx[d] = ((unsigned)g < (unsigned)HW2) ? RW[d] : 0.0f; sumx += wx[d];
  }
  const float inv = 1.0f / (sumy * sumx);

  __syncthreads();
  eval_round(s_src, s_tile, res0, res1, pt, tid);
  __syncthreads();

  float acc0 = 0.0f, acc1 = 0.0f;
  #pragma unroll
  for (int dy = 0; dy < 4; ++dy) {
    float r0 = 0.0f, r1 = 0.0f;
    const int base = (2 * ly + dy) * 34 + 2 * lx;
    #pragma unroll
    for (int dx = 0; dx < 4; ++dx) {
      float2 v = s_tile[base + dx];
      r0 += wx[dx] * v.x;
      r1 += wx[dx] * v.y;
    }
    acc0 += wy[dy] * r0;
    acc1 += wy[dy] * r1;
  }
  size_t o = ((size_t)b * 2) * SZ + (size_t)oy * HW + ox;
  nres[o]      = acc0 * inv + adjx[(size_t)oy * HW + ox];
  nres[o + SZ] = acc1 * inv + adjy[(size_t)oy * HW + ox];
}

extern "C" void kernel_launch(void* const* d_in, const int* in_sizes, int n_in,
                              void* d_out, int out_size, void* d_ws, size_t ws_size,
                              hipStream_t stream) {
  const float* x   = (const float*)d_in[0];  // [2,32,512,512] f32
  const float* res = (const float*)d_in[1];  // [2,2,512,512]  f32
  const float* Wc  = (const float*)d_in[2];  // [2,50,3,3]     f32
  const float* bc  = (const float*)d_in[3];  // [2]            f32
  float* out = (float*)d_out;                // [2,32,512,512] f32

  float* adj  = (float*)d_ws;                // [2,2,512,512]
  float* nres = adj + (size_t)2 * 2 * SZ;    // [2,2,512,512]

  dim3 tile_grid(32, 32, 2);

  // K1: warped_tgt -> out channels 16..31 (fp32 staging for conv)
  warp_img_kernel<<<tile_grid, dim3(256), 0, stream>>>(x, res, out);

  // K2: conv3x3 over [x(0..31) | out(16..31) | res] -> adj, plus fused src passthrough
  conv_kernel<<<tile_grid, dim3(256), 0, stream>>>(x, res, Wc, bc, out, adj);

  // K3: new_res
  new_res_kernel<<<tile_grid, dim3(256), 0, stream>>>(res, adj, nres);

  // K4: hindsight warp -> out channels 16..31 (overwrites staging)
  warp_img_kernel<<<tile_grid, dim3(256), 0, stream>>>(x, nres, out);
}

// Round 6
// 371.817 us; speedup vs baseline: 1.1851x; 1.0151x over previous
//
#include <hip/hip_runtime.h>
#include <hip/hip_bf16.h>
#include <cstdint>
#include <cstddef>

// Problem constants
#define HW   512
#define HW2  1024
#define SZ   (512 * 512)
#define NPT  (34 * 34)   // 1156 warped 1024-res points per 16x16 output tile
#define K_PTS 5          // ceil(1156 / 256)
#define SRCW 36          // staged source window: 36x36
#define NSRC (SRCW * SRCW)   // 1296
#define MARG 9           // window origin = tile_origin - MARG
#define FDIM 18          // staged field window: rows/cols [t0-1, t0+16]
#define NFLD (FDIM * FDIM)   // 324

// jax.image.resize bilinear upsample 512->1024 taps for output index i (0..1023)
struct UpTap { int i0, i1; float w0, w1; };

__device__ __forceinline__ UpTap up_tap(int i) {
  UpTap t;
  int k = i >> 1;
  if ((i & 1) == 0) {
    t.i0 = k - 1; t.i1 = k; t.w0 = 0.25f; t.w1 = 0.75f;
    if (k == 0) { t.i0 = 0; t.w0 = 0.0f; t.w1 = 1.0f; }
  } else {
    t.i0 = k; t.i1 = k + 1; t.w0 = 0.75f; t.w1 = 0.25f;
    if (k == HW - 1) { t.i1 = HW - 1; t.w0 = 1.0f; t.w1 = 0.0f; }
  }
  return t;
}

// Both warp-field components, bilinear-upsampled, served from the staged LDS tile.
// Arithmetic identical (per component) to the original global-memory up_at.
__device__ __forceinline__ float2 up_at2(const float2* __restrict__ f,
                                         int yi, int xi, int oy, int ox) {
  UpTap ty = up_tap(yi), tx = up_tap(xi);
  const float2* r0 = f + (ty.i0 - oy) * FDIM - ox;
  const float2* r1 = f + (ty.i1 - oy) * FDIM - ox;
  float2 v00 = r0[tx.i0], v01 = r0[tx.i1];
  float2 v10 = r1[tx.i0], v11 = r1[tx.i1];
  float2 r;
  r.x = ty.w0 * (tx.w0 * v00.x + tx.w1 * v01.x) + ty.w1 * (tx.w0 * v10.x + tx.w1 * v11.x);
  r.y = ty.w0 * (tx.w0 * v00.y + tx.w1 * v01.y) + ty.w1 * (tx.w0 * v10.y + tx.w1 * v11.y);
  return r;
}

// Separable decomposition of (warp-bilinear in 1024-space) o (2x upsample):
// a 3-tap stencil on the 512 grid. Base clamped to [0,509]; out-of-range
// corners get weight 0 (zero padding, mask pre-clamp).
__device__ __forceinline__ void axis_taps(float s, int& base, float& w0, float& w1, float& w2) {
  float f0 = floorf(s);
  int i0 = (int)f0;
  float fr = s - f0;
  int b = (i0 & 1) ? (i0 >> 1) : (i0 >> 1) - 1;
  b = b < 0 ? 0 : (b > (HW - 3) ? (HW - 3) : b);
  float w[3] = {0.0f, 0.0f, 0.0f};
  if ((unsigned)i0 < (unsigned)HW2) {
    UpTap t = up_tap(i0);
    w[t.i0 - b] += (1.0f - fr) * t.w0;
    w[t.i1 - b] += (1.0f - fr) * t.w1;
  }
  if ((unsigned)(i0 + 1) < (unsigned)HW2) {
    UpTap t = up_tap(i0 + 1);
    w[t.i0 - b] += fr * t.w0;
    w[t.i1 - b] += fr * t.w1;
  }
  base = b; w0 = w[0]; w1 = w[1]; w2 = w[2];
}

// Per-point separable 3x3 stencil. locoff >= 0: index into staged 36x36 LDS window.
// locoff < 0: rare fallback, ~locoff = global by*HW+bx offset (displacement > ~8px).
struct PtTaps {
  int   locoff;
  float wy0, wy1, wy2, wx0, wx1, wx2;
};

// Stage the 18x18 field window (fx,fy interleaved) into LDS. Clamped coords:
// clamped slots are only read via up_tap's pre-clamped indices or with weight 0.
__device__ __forceinline__ void stage_field(const float* __restrict__ fx,
                                            const float* __restrict__ fy,
                                            float2* __restrict__ sf,
                                            int fy0, int fx0, int tid) {
  #pragma unroll
  for (int i = 0; i < 2; ++i) {
    int p = tid + i * 256;
    if (p < NFLD) {
      int r = p / FDIM, c = p % FDIM;
      int gy = fy0 + r; gy = gy < 0 ? 0 : (gy > HW - 1 ? HW - 1 : gy);
      int gx = fx0 + c; gx = gx < 0 ? 0 : (gx > HW - 1 ? HW - 1 : gx);
      size_t o = (size_t)gy * HW + gx;
      sf[p] = make_float2(fx[o], fy[o]);
    }
  }
}

// Taps from the LDS-staged field (no global loads).
__device__ __forceinline__ void compute_taps(const float2* __restrict__ sf,
                                             int fy0, int fx0,
                                             int gx0, int gy0, int xo, int yo, int tid,
                                             PtTaps (&pt)[K_PTS]) {
  #pragma unroll
  for (int i = 0; i < K_PTS; ++i) {
    int p = tid + i * 256;
    pt[i].locoff = 0;
    pt[i].wy0 = pt[i].wy1 = pt[i].wy2 = 0.0f;
    pt[i].wx0 = pt[i].wx1 = pt[i].wx2 = 0.0f;
    if (p < NPT) {
      int ry = p / 34, rx = p % 34;
      int yy = gy0 + ry, xx = gx0 + rx;
      if ((unsigned)yy < (unsigned)HW2 && (unsigned)xx < (unsigned)HW2) {
        float2 d = up_at2(sf, yy, xx, fy0, fx0);
        float sx = (float)xx + 2.0f * d.x;
        float sy = (float)yy + 2.0f * d.y;
        int bx, by;
        axis_taps(sx, bx, pt[i].wx0, pt[i].wx1, pt[i].wx2);
        axis_taps(sy, by, pt[i].wy0, pt[i].wy1, pt[i].wy2);
        int rx_ = bx - xo, ry_ = by - yo;
        if ((unsigned)rx_ <= (unsigned)(SRCW - 3) && (unsigned)ry_ <= (unsigned)(SRCW - 3))
          pt[i].locoff = ry_ * SRCW + rx_;          // in staged window
        else
          pt[i].locoff = ~(by * HW + bx);           // fallback: global offset
      }
    }
  }
}

// Stage a channel pair's 36x36 source window into LDS (float2 interleaved).
__device__ __forceinline__ void stage_pair(const float* __restrict__ p0,
                                           const float* __restrict__ p1,
                                           float2* __restrict__ s_src,
                                           int xo, int yo, int tid) {
  #pragma unroll
  for (int i = 0; i < 6; ++i) {                   // 6*256 = 1536 >= 1296
    int p = tid + i * 256;
    if (p < NSRC) {
      int r = p / SRCW, c = p % SRCW;
      int gy = yo + r; gy = gy < 0 ? 0 : (gy > HW - 1 ? HW - 1 : gy);
      int gx = xo + c; gx = gx < 0 ? 0 : (gx > HW - 1 ? HW - 1 : gx);
      size_t o = (size_t)gy * HW + gx;
      s_src[p] = make_float2(p0[o], p1[o]);
    }
  }
}

__device__ __forceinline__ float eval3_global(const float* __restrict__ pl, int off, const PtTaps& t) {
  const float* p0 = pl + off;
  float r0 = t.wx0 * p0[0]        + t.wx1 * p0[1]          + t.wx2 * p0[2];
  float r1 = t.wx0 * p0[HW]       + t.wx1 * p0[HW + 1]     + t.wx2 * p0[HW + 2];
  float r2 = t.wx0 * p0[2 * HW]   + t.wx1 * p0[2 * HW + 1] + t.wx2 * p0[2 * HW + 2];
  return t.wy0 * r0 + t.wy1 * r1 + t.wy2 * r2;
}

// Evaluate all points of a channel pair from the staged LDS window into s_tile.
__device__ __forceinline__ void eval_round(const float2* __restrict__ s_src,
                                           float2* __restrict__ s_tile,
                                           const float* __restrict__ plane0,
                                           const float* __restrict__ plane1,
                                           const PtTaps (&pt)[K_PTS], int tid) {
  #pragma unroll
  for (int i = 0; i < K_PTS; ++i) {
    int p = tid + i * 256;
    if (p < NPT) {
      const PtTaps t = pt[i];
      float a0, a1;
      if (t.locoff >= 0) {
        const float2* s = s_src + t.locoff;
        float2 v00 = s[0],        v01 = s[1],            v02 = s[2];
        float2 v10 = s[SRCW],     v11 = s[SRCW + 1],     v12 = s[SRCW + 2];
        float2 v20 = s[2 * SRCW], v21 = s[2 * SRCW + 1], v22 = s[2 * SRCW + 2];
        float r00 = t.wx0 * v00.x + t.wx1 * v01.x + t.wx2 * v02.x;
        float r10 = t.wx0 * v10.x + t.wx1 * v11.x + t.wx2 * v12.x;
        float r20 = t.wx0 * v20.x + t.wx1 * v21.x + t.wx2 * v22.x;
        float r01 = t.wx0 * v00.y + t.wx1 * v01.y + t.wx2 * v02.y;
        float r11 = t.wx0 * v10.y + t.wx1 * v11.y + t.wx2 * v12.y;
        float r21 = t.wx0 * v20.y + t.wx1 * v21.y + t.wx2 * v22.y;
        a0 = t.wy0 * r00 + t.wy1 * r10 + t.wy2 * r20;
        a1 = t.wy0 * r01 + t.wy1 * r11 + t.wy2 * r21;
      } else {                                     // ~never taken (|disp| > ~8px)
        int off = ~t.locoff;
        a0 = eval3_global(plane0, off, t);
        a1 = eval3_global(plane1, off, t);
      }
      s_tile[p] = make_float2(a0, a1);
    }
  }
}

// -------------------- K1/K4: res_warp_img(tgt, res_field, rollback=1) --------------------
// Round-1 structure (VGPR=64 invariant) + LDS-staged warp field for the tap phase.
// Field tile lives in the s_tile buffer (dead until first eval round).
__global__ void warp_img_kernel(const float* __restrict__ x,    // [B,32,512,512]
                                const float* __restrict__ res,  // [B,2,512,512]
                                float* __restrict__ out)        // [B,32,512,512]
{
  __shared__ float2 s_src[NSRC];   // 10368 B
  __shared__ float2 s_tile[NPT];   //  9248 B  (prologue: holds the 18x18 field tile)

  const int b = blockIdx.z;
  const int tx0 = blockIdx.x * 16, ty0 = blockIdx.y * 16;
  const int gx0 = tx0 * 2 - 1, gy0 = ty0 * 2 - 1;
  const int xo = tx0 - MARG, yo = ty0 - MARG;
  const int fy0 = ty0 - 1, fx0 = tx0 - 1;
  const int tid = threadIdx.x;

  const float* resx = res + (size_t)b * 2 * SZ;
  const float* resy = resx + SZ;
  const float* tgt  = x + ((size_t)b * 32 + 16) * SZ;

  // Issue round-0 channel staging + field staging together.
  stage_pair(tgt, tgt + SZ, s_src, xo, yo, tid);
  stage_field(resx, resy, s_tile, fy0, fx0, tid);

  // Downsample stencil weights for this thread's output pixel
  const int ly = tid >> 4, lx = tid & 15;
  const int oy = ty0 + ly, ox = tx0 + lx;
  const float RW[4] = {0.25f, 0.75f, 0.75f, 0.25f};
  float wy[4], wx[4];
  float sumy = 0.f, sumx = 0.f;
  #pragma unroll
  for (int d = 0; d < 4; ++d) {
    int g = 2 * oy - 1 + d;
    wy[d] = ((unsigned)g < (unsigned)HW2) ? RW[d] : 0.0f; sumy += wy[d];
    g = 2 * ox - 1 + d;
    wx[d] = ((unsigned)g < (unsigned)HW2) ? RW[d] : 0.0f; sumx += wx[d];
  }
  const float inv = 1.0f / (sumy * sumx);

  __syncthreads();                                 // field + round-0 src ready

  PtTaps pt[K_PTS];
  compute_taps(s_tile, fy0, fx0, gx0, gy0, xo, yo, tid, pt);

  __syncthreads();                                 // field reads done; s_tile free

  for (int c = 0; c < 16; c += 2) {
    const float* plane0 = tgt + (size_t)c * SZ;
    eval_round(s_src, s_tile, plane0, plane0 + SZ, pt, tid);
    __syncthreads();                               // s_tile ready; s_src free

    if (c < 14)                                    // overlap next staging with phase 3
      stage_pair(plane0 + 2 * SZ, plane0 + 3 * SZ, s_src, xo, yo, tid);

    float acc0 = 0.0f, acc1 = 0.0f;
    #pragma unroll
    for (int dy = 0; dy < 4; ++dy) {
      float r0 = 0.0f, r1 = 0.0f;
      const int base = (2 * ly + dy) * 34 + 2 * lx;
      #pragma unroll
      for (int dx = 0; dx < 4; ++dx) {
        float2 v = s_tile[base + dx];
        r0 += wx[dx] * v.x;
        r1 += wx[dx] * v.y;
      }
      acc0 += wy[dy] * r0;
      acc1 += wy[dy] * r1;
    }
    size_t o = (((size_t)b * 32 + 16 + c) * HW + oy) * HW + ox;
    out[o] = acc0 * inv;
    out[o + SZ] = acc1 * inv;
    __syncthreads();                               // s_src(next) ready; s_tile free
  }
}

// -------------------- K2: 3x3 conv over 50-ch bundle -> 2-ch adj --------------------
// Quad-processed (12 iters x 4 planes + 1 res pair): halves barrier count vs pairs,
// doubles the compute window covering the prefetch (T14 write-late). Fused src
// passthrough: out ch 0..15 = center taps of the staged halos (replaces copy kernel).
#define CHN 18                     // halo width (16 + 2)
#define CHE (CHN * CHN)            // 324 elements

__global__ void __launch_bounds__(256)
conv_kernel(const float* __restrict__ x,
            const float* __restrict__ res,
            const float* __restrict__ Wc,      // [2,50,3,3]
            const float* __restrict__ bc,      // [2]
            float* __restrict__ out,           // [B,32,512,512]: reads ch16..31 (warped), writes ch0..15
            float* __restrict__ adj)           // [B,2,512,512]
{
  __shared__ float sw[900];
  __shared__ float sh[8][CHE];     // two quad-buffers (4 planes each)

  const int tid = threadIdx.x;
  for (int i = tid; i < 900; i += 256) sw[i] = Wc[i];

  const int b = blockIdx.z;
  const int tx0 = blockIdx.x * 16, ty0 = blockIdx.y * 16;
  const int ty = tid >> 4, tx = tid & 15;

  const float* px = x + (size_t)b * 32 * SZ;
  const float* pw = out + ((size_t)b * 32 + 16) * SZ;
  const float* pr = res + (size_t)b * 2 * SZ;

  // Halo-slot addressing (identical for every plane; computed once)
  const int ry0 = tid / CHN, rx0 = tid - ry0 * CHN;
  const int hy0 = ty0 - 1 + ry0, hx0 = tx0 - 1 + rx0;
  const bool ok0 = (unsigned)hy0 < (unsigned)HW && (unsigned)hx0 < (unsigned)HW;
  const int off0 = hy0 * HW + hx0;               // only deref'd under ok0
  const int p1 = tid + 256;
  const bool sl1 = p1 < CHE;                     // tid < 68
  const int ry1 = p1 / CHN, rx1 = p1 - ry1 * CHN;
  const int hy1 = ty0 - 1 + ry1, hx1 = tx0 - 1 + rx1;
  const bool ok1 = sl1 && (unsigned)hy1 < (unsigned)HW && (unsigned)hx1 < (unsigned)HW;
  const int off1 = hy1 * HW + hx1;

  #define PLANE(ic) ((ic) < 32 ? px + (size_t)(ic) * SZ \
                   : (ic) < 48 ? pw + (size_t)((ic) - 32) * SZ \
                   : pr + (size_t)((ic) - 48) * SZ)

  float acc0 = bc[0];
  float acc1 = bc[1];

  float q0[4], q1[4];
  {  // prologue: stage quad 0 (planes 0..3) into sh[0..3]
    #pragma unroll
    for (int j = 0; j < 4; ++j) {
      const float* pl = PLANE(j);
      q0[j] = ok0 ? pl[off0] : 0.f;
      q1[j] = ok1 ? pl[off1] : 0.f;
    }
    #pragma unroll
    for (int j = 0; j < 4; ++j) {
      sh[j][tid] = q0[j];
      if (sl1) sh[j][p1] = q1[j];
    }
  }

  const size_t pix = (size_t)(ty0 + ty) * HW + (tx0 + tx);

  for (int kk = 0; kk < 12; ++kk) {
    __syncthreads();                      // current quad ready; other quad free
    if (kk < 11) {                        // issue next quad's loads before compute (T14)
      #pragma unroll
      for (int j = 0; j < 4; ++j) {
        const float* pl = PLANE(4 * kk + 4 + j);
        q0[j] = ok0 ? pl[off0] : 0.f;
        q1[j] = ok1 ? pl[off1] : 0.f;
      }
    } else {                              // last: stage the res pair (ch 48,49)
      #pragma unroll
      for (int j = 0; j < 2; ++j) {
        const float* pl = PLANE(48 + j);
        q0[j] = ok0 ? pl[off0] : 0.f;
        q1[j] = ok1 ? pl[off1] : 0.f;
      }
    }

    const int cur = (kk & 1) * 4;
    float cen[4];
    #pragma unroll
    for (int ky = 0; ky < 3; ++ky) {
      #pragma unroll
      for (int kx = 0; kx < 3; ++kx) {
        const int hoff = (ty + ky) * CHN + tx + kx;
        const int widx = ky * 3 + kx;
        #pragma unroll
        for (int j = 0; j < 4; ++j) {
          float v = sh[cur + j][hoff];
          if (ky == 1 && kx == 1) cen[j] = v;
          acc0 += v * sw[(4 * kk + j) * 9 + widx];
          acc1 += v * sw[450 + (4 * kk + j) * 9 + widx];
        }
      }
    }

    if (kk < 4) {                         // fused K0: out ch 4kk..4kk+3 = x ch 4kk..4kk+3
      #pragma unroll
      for (int j = 0; j < 4; ++j)
        out[((size_t)b * 32 + 4 * kk + j) * SZ + pix] = cen[j];
    }

    const int nxt = cur ^ 4;              // write-late into the other quad-buffer
    if (kk < 11) {
      #pragma unroll
      for (int j = 0; j < 4; ++j) {
        sh[nxt + j][tid] = q0[j];
        if (sl1) sh[nxt + j][p1] = q1[j];
      }
    } else {
      #pragma unroll
      for (int j = 0; j < 2; ++j) {
        sh[nxt + j][tid] = q0[j];
        if (sl1) sh[nxt + j][p1] = q1[j];
      }
    }
  }

  // epilogue: res pair (ch 48,49) sits in sh[0],sh[1] (nxt of kk=11 -> cur flips to 0)
  __syncthreads();
  #pragma unroll
  for (int ky = 0; ky < 3; ++ky) {
    #pragma unroll
    for (int kx = 0; kx < 3; ++kx) {
      const int hoff = (ty + ky) * CHN + tx + kx;
      const int widx = ky * 3 + kx;
      #pragma unroll
      for (int j = 0; j < 2; ++j) {
        float v = sh[j][hoff];
        acc0 += v * sw[(48 + j) * 9 + widx];
        acc1 += v * sw[450 + (48 + j) * 9 + widx];
      }
    }
  }
  #undef PLANE

  adj[((size_t)b * 2 + 0) * SZ + pix] = acc0;
  adj[((size_t)b * 2 + 1) * SZ + pix] = acc1;
}

// -------------------- K3: new_res = adj + downsample(warp(up(res), 2*up(adj))) --------------------
// (the reference's *2 on the warped field values and the *0.5 after downsample cancel exactly)
__global__ void new_res_kernel(const float* __restrict__ res,  // [B,2,512,512]
                               const float* __restrict__ adj,  // [B,2,512,512]
                               float* __restrict__ nres)       // [B,2,512,512]
{
  __shared__ float2 s_src[NSRC];
  __shared__ float2 s_tile[NPT];

  const int b = blockIdx.z;
  const int tx0 = blockIdx.x * 16, ty0 = blockIdx.y * 16;
  const int gx0 = tx0 * 2 - 1, gy0 = ty0 * 2 - 1;
  const int xo = tx0 - MARG, yo = ty0 - MARG;
  const int fy0 = ty0 - 1, fx0 = tx0 - 1;
  const int tid = threadIdx.x;

  const float* adjx = adj + (size_t)b * 2 * SZ;
  const float* adjy = adjx + SZ;
  const float* res0 = res + (size_t)b * 2 * SZ;
  const float* res1 = res0 + SZ;

  stage_pair(res0, res1, s_src, xo, yo, tid);
  stage_field(adjx, adjy, s_tile, fy0, fx0, tid);

  const int ly = tid >> 4, lx = tid & 15;
  const int oy = ty0 + ly, ox = tx0 + lx;
  const float RW[4] = {0.25f, 0.75f, 0.75f, 0.25f};
  float wy[4], wx[4];
  float sumy = 0.f, sumx = 0.f;
  #pragma unroll
  for (int d = 0; d < 4; ++d) {
    int g = 2 * oy - 1 + d;
    wy[d] = ((unsigned)g < (unsigned)HW2) ? RW[d] : 0.0f; sumy += wy[d];
    g = 2 * ox - 1 + d;
    wx[d] = ((unsigned)g < (unsigned)HW2) ? RW[d] : 0.0f; sumx += wx[d];
  }
  const float inv = 1.0f / (sumy * sumx);

  __syncthreads();                                 // field + src ready

  PtTaps pt[K_PTS];
  compute_taps(s_tile, fy0, fx0, gx0, gy0, xo, yo, tid, pt);

  __syncthreads();                                 // field reads done; s_tile free

  eval_round(s_src, s_tile, res0, res1, pt, tid);
  __syncthreads();

  float acc0 = 0.0f, acc1 = 0.0f;
  #pragma unroll
  for (int dy = 0; dy < 4; ++dy) {
    float r0 = 0.0f, r1 = 0.0f;
    const int base = (2 * ly + dy) * 34 + 2 * lx;
    #pragma unroll
    for (int dx = 0; dx < 4; ++dx) {
      float2 v = s_tile[base + dx];
      r0 += wx[dx] * v.x;
      r1 += wx[dx] * v.y;
    }
    acc0 += wy[dy] * r0;
    acc1 += wy[dy] * r1;
  }
  size_t o = ((size_t)b * 2) * SZ + (size_t)oy * HW + ox;
  nres[o]      = acc0 * inv + adjx[(size_t)oy * HW + ox];
  nres[o + SZ] = acc1 * inv + adjy[(size_t)oy * HW + ox];
}

extern "C" void kernel_launch(void* const* d_in, const int* in_sizes, int n_in,
                              void* d_out, int out_size, void* d_ws, size_t ws_size,
                              hipStream_t stream) {
  const float* x   = (const float*)d_in[0];  // [2,32,512,512] f32
  const float* res = (const float*)d_in[1];  // [2,2,512,512]  f32
  const float* Wc  = (const float*)d_in[2];  // [2,50,3,3]     f32
  const float* bc  = (const float*)d_in[3];  // [2]            f32
  float* out = (float*)d_out;                // [2,32,512,512] f32

  float* adj  = (float*)d_ws;                // [2,2,512,512]
  float* nres = adj + (size_t)2 * 2 * SZ;    // [2,2,512,512]

  dim3 tile_grid(32, 32, 2);

  // K1: warped_tgt -> out channels 16..31 (fp32 staging for conv)
  warp_img_kernel<<<tile_grid, dim3(256), 0, stream>>>(x, res, out);

  // K2: conv3x3 over [x(0..31) | out(16..31) | res] -> adj, plus fused src passthrough
  conv_kernel<<<tile_grid, dim3(256), 0, stream>>>(x, res, Wc, bc, out, adj);

  // K3: new_res
  new_res_kernel<<<tile_grid, dim3(256), 0, stream>>>(res, adj, nres);

  // K4: hindsight warp -> out channels 16..31 (overwrites staging)
  warp_img_kernel<<<tile_grid, dim3(256), 0, stream>>>(x, nres, out);
}